// Round 9
// baseline (309.102 us; speedup 1.0000x reference)
//
#include <hip/hip_runtime.h>
#include <hip/hip_bf16.h>

// RecurrentLSTMStack: T=256, B=2048, D=16, H=64, 3 layers.
// R9: R8 16-wave structure (grid 256, 1024 thr, 2-seq nonlin) +
//  - paired-tile LDS reads: dup-lane pairs (c,c+8) read even/odd K-tiles,
//    DPP row_ror:8 exchange + cndmask -> 4 ds_read_b128/wave (LDS/CU 112->64;
//    LDS pipe is the most-loaded resource at 16 waves per R7/R8 calibration)
//  - log2e folded into weights/biases at init (i,f,o rows x1.4427, g rows
//    x2.8854): saves 4 v_mul/seq; exp2(-x) via free neg modifier
//  - SROW=216 (starts 4*(3r+g+2m) mod 32: uniform 8/slot, best possible)

#define TT 256
#define BB 2048
#define DD 16
#define HH 64

#define SROW 216                 // halves/row = 108 dwords
#define PANEL (8 * SROW)         // 1728 halves per parity panel
#define H0O 0
#define H1O 64
#define H2O 128
#define XO  192

#define L2E  1.4426950408889634f
#define L2E2 2.8853900817779268f

typedef __attribute__((ext_vector_type(8))) _Float16 halfx8;
typedef __attribute__((ext_vector_type(8))) unsigned short ushortx8;
typedef __attribute__((ext_vector_type(4))) float floatx4;

#if __has_builtin(__builtin_amdgcn_exp2f)
#define EXP2F(x) __builtin_amdgcn_exp2f(x)
#else
#define EXP2F(x) exp2f(x)
#endif
#if __has_builtin(__builtin_amdgcn_rcpf)
#define RCPF(x) __builtin_amdgcn_rcpf(x)
#else
#define RCPF(x) (1.0f/(x))
#endif

// inputs pre-scaled by L2E (sigm) / L2E2 (tanh args)
__device__ __forceinline__ float sigm_s(float xs) {   // x' = L2E*x
  return RCPF(1.0f + EXP2F(-xs));
}
__device__ __forceinline__ float tanh_s(float xs) {   // x' = L2E2*x
  return 1.0f - 2.0f * RCPF(EXP2F(xs) + 1.0f);
}
// Raw barrier: waits our ds ops, does NOT drain vmcnt (x prefetch + out stores
// stay in flight).
__device__ __forceinline__ void block_sync() {
  asm volatile("s_waitcnt lgkmcnt(0)" ::: "memory");
  __builtin_amdgcn_s_barrier();
}

// VALU-pipe lane exchange c <-> c+8 within each 16-lane DPP row (row_ror:8).
__device__ __forceinline__ halfx8 dpp_xor8(halfx8 v) {
  union { halfx8 h; int i[4]; } u, d;
  u.h = v;
#pragma unroll
  for (int k = 0; k < 4; ++k)
    d.i[k] = __builtin_amdgcn_update_dpp(0, u.i[k], 0x128, 0xf, 0xf, true);
  return d.h;
}

__global__ void detect_k(const unsigned short* __restrict__ xr, int* __restrict__ flag) {
  int cnt = 0;
  for (int i = threadIdx.x; i < 4096; i += 64) {
    float v = __uint_as_float(((unsigned int)xr[i]) << 16);
    if (!(fabsf(v) < 4.0f)) cnt++;
  }
#pragma unroll
  for (int o = 32; o > 0; o >>= 1) cnt += __shfl_down(cnt, o, 64);
  if (threadIdx.x == 0) flag[0] = (cnt < 100) ? 1 : 0;
}

#define MF(A, B, C) __builtin_amdgcn_mfma_f32_16x16x32_f16(A, B, C, 0, 0, 0)

#define BODY(S_, PPB, PNB)                                                        \
  {                                                                               \
    const int s_ = (S_);                                                          \
    halfx8 xreg = {};                                                             \
    const bool loader = (tid < 16) && (s_ + 1 < TT);                              \
    if (loader)                                                                   \
      xreg = ld8(xg, ((long)(s_ + 1) * BB + rowbase + (tid >> 1)) * DD + (tid & 1) * 8); \
    block_sync();                                                                 \
    const _Float16* PpR = SH + (PPB) + rd_offP;                                   \
    _Float16* Pn = SH + (PNB);                                                    \
    halfx8 pA = *(const halfx8*)(PpR + 0);      /* h0 even|odd K-tile */          \
    halfx8 pB = *(const halfx8*)(PpR + 64);     /* h1 */                          \
    halfx8 pC = *(const halfx8*)(PpR + 128);    /* h2 */                          \
    halfx8 rX = *(const halfx8*)(SH + (PPB) + rd_offX);  /* x tile (all) */       \
    halfx8 sA = dpp_xor8(pA);                                                     \
    halfx8 sB = dpp_xor8(pB);                                                     \
    halfx8 sC = dpp_xor8(pC);                                                     \
    halfx8 r0 = m8 ? sA : pA, r1 = m8 ? pA : sA;                                  \
    halfx8 r2 = m8 ? sB : pB, r3 = m8 ? pB : sB;                                  \
    halfx8 r4 = m8 ? sC : pC, r5 = m8 ? pC : sC;                                  \
    floatx4 a0 = bs0, a1 = bs1, a2 = bs2;                                         \
    __builtin_amdgcn_s_setprio(1);                                                \
    a0 = MF(wA0[0], r0, a0); a2 = MF(wA2[0], r2, a2);                             \
    a0 = MF(wA0[1], r1, a0); a2 = MF(wA2[1], r3, a2);                             \
    a2 = MF(wA2[2], r4, a2); a0 = MF(wA0[2], rX, a0);                             \
    a2 = MF(wA2[3], r5, a2);                                                      \
    a1 = MF(wA1[0], r0, a1); a1 = MF(wA1[1], r1, a1);                             \
    a1 = MF(wA1[2], r2, a1); a1 = MF(wA1[3], r3, a1);                             \
    __builtin_amdgcn_s_setprio(0);                                                \
    { /* seq A: lanes c<8 -> L0 cell, lanes m8 -> L2 cell */                      \
      floatx4 gv;                                                                 \
      gv[0] = m8 ? a2[0] : a0[0]; gv[1] = m8 ? a2[1] : a0[1];                     \
      gv[2] = m8 ? a2[2] : a0[2]; gv[3] = m8 ? a2[3] : a0[3];                     \
      float I = sigm_s(gv[0]), F = sigm_s(gv[1]);                                 \
      float G = tanh_s(gv[2]), O = sigm_s(gv[3]);                                 \
      float cn = F * cA + I * G;                                                  \
      float hn = O * tanh_s(L2E2 * cn);                                           \
      bool vA = m8 ? (s_ >= 2) : (s_ < TT);                                       \
      if (vA) {                                                                   \
        cA = cn; Pn[wrA] = (_Float16)hn;                                          \
        if (m8) {                                                                 \
          long oi = (long)(s_ - 2) * ((long)BB * HH) + olane;                     \
          if (isbf) ((__hip_bfloat16*)outp)[oi] = __float2bfloat16(hn);           \
          else ((float*)outp)[oi] = hn;                                           \
        }                                                                         \
      }                                                                           \
    }                                                                             \
    { /* seq B: lanes c<8 -> L1 cell */                                           \
      float I = sigm_s(a1[0]), F = sigm_s(a1[1]);                                 \
      float G = tanh_s(a1[2]), O = sigm_s(a1[3]);                                 \
      float cn = F * cB + I * G;                                                  \
      float hn = O * tanh_s(L2E2 * cn);                                           \
      if (!m8 && s_ >= 1 && s_ <= TT) { cB = cn; Pn[wrB] = (_Float16)hn; }        \
    }                                                                             \
    if (loader) *(halfx8*)&Pn[(tid >> 1) * SROW + XO + (tid & 1) * 8] = xreg;     \
  }

__launch_bounds__(1024, 1)
__global__ void lstm3_k(const void* __restrict__ xg,
                        const void* W0i, const void* W0h, const void* B0i, const void* B0h,
                        const void* W1i, const void* W1h, const void* B1i, const void* B1h,
                        const void* W2i, const void* W2h, const void* B2i, const void* B2h,
                        void* __restrict__ outp, const int* __restrict__ flagp) {
  const int tid = threadIdx.x;
  const int W = tid >> 6;        // wave 0..15 = M-tile index
  const int lane = tid & 63;
  const int c = lane & 15;       // MFMA col (batch row c&7, dup pair c/c+8)
  const int g = lane >> 4;       // k-slot group
  const int rowbase = blockIdx.x * 8;
  const int isbf = flagp ? flagp[0] : 1;

  // Panel row r: [h0(0..63) | h1(64..127) | h2(128..191) | x(192..207) | pad(..215)]
  // +32 zeroed tail: parity-1 row-7 g=3 x-tile over-read (weights zero there).
  __shared__ __align__(16) _Float16 SH[2 * PANEL + 32];

  auto ldf = [&](const void* b, long i) -> float {
    return isbf ? __bfloat162float(((const __hip_bfloat16*)b)[i]) : ((const float*)b)[i];
  };
  auto ld8 = [&](const void* b, long i) -> halfx8 {
    halfx8 r;
    if (isbf) {
      ushortx8 raw = *(const ushortx8*)((const unsigned short*)b + i);
#pragma unroll
      for (int j = 0; j < 8; ++j)
        r[j] = (_Float16)__uint_as_float(((unsigned int)raw[j]) << 16);
    } else {
      const float* s = (const float*)b + i;
#pragma unroll
      for (int j = 0; j < 8; ++j) r[j] = (_Float16)s[j];
    }
    return r;
  };
  auto ld8s = [&](const void* b, long i, float sc) -> halfx8 {  // scaled weight load
    halfx8 r;
    if (isbf) {
      ushortx8 raw = *(const ushortx8*)((const unsigned short*)b + i);
#pragma unroll
      for (int j = 0; j < 8; ++j)
        r[j] = (_Float16)(sc * __uint_as_float(((unsigned int)raw[j]) << 16));
    } else {
      const float* s = (const float*)b + i;
#pragma unroll
      for (int j = 0; j < 8; ++j) r[j] = (_Float16)(sc * s[j]);
    }
    return r;
  };

  // ---- persistent weight fragments (ONE M-tile per wave) + combined biases ----
  // Interleaved gate rows: r_il = 4*unit + q <-> orig row q*64 + unit.
  // Gate q scale: i,f,o -> L2E; g -> L2E2 (folded log2e; exp2 used directly).
  halfx8 wA0[3], wA1[4], wA2[4];
  floatx4 bs0, bs1, bs2;
  {
    const int ril = W * 16 + c;
    const int u = ril >> 2, q = ril & 3;
    const long orig = q * 64 + u;
    const float sc = (q == 2) ? L2E2 : L2E;
    halfx8 z = {};
    wA0[0] = ld8s(W0h, orig * 64 + 8 * g, sc);
    wA0[1] = ld8s(W0h, orig * 64 + 32 + 8 * g, sc);
    wA0[2] = (g == 0) ? ld8s(W0i, orig * 16, sc)
           : (g == 1) ? ld8s(W0i, orig * 16 + 8, sc) : z;
    wA1[0] = ld8s(W1i, orig * 64 + 8 * g, sc);
    wA1[1] = ld8s(W1i, orig * 64 + 32 + 8 * g, sc);
    wA1[2] = ld8s(W1h, orig * 64 + 8 * g, sc);
    wA1[3] = ld8s(W1h, orig * 64 + 32 + 8 * g, sc);
    wA2[0] = ld8s(W2i, orig * 64 + 8 * g, sc);
    wA2[1] = ld8s(W2i, orig * 64 + 32 + 8 * g, sc);
    wA2[2] = ld8s(W2h, orig * 64 + 8 * g, sc);
    wA2[3] = ld8s(W2h, orig * 64 + 32 + 8 * g, sc);
    // C-layout: lane (c,g) reg qq = gate row W*16 + 4g + qq = (unit 4W+g, gate qq)
    const int ub = 4 * W + g;
#pragma unroll
    for (int qq = 0; qq < 4; ++qq) {
      const float bsc = (qq == 2) ? L2E2 : L2E;
      bs0[qq] = bsc * (ldf(B0i, 64 * qq + ub) + ldf(B0h, 64 * qq + ub));
      bs1[qq] = bsc * (ldf(B1i, 64 * qq + ub) + ldf(B1h, 64 * qq + ub));
      bs2[qq] = bsc * (ldf(B2i, 64 * qq + ub) + ldf(B2h, 64 * qq + ub));
    }
  }

  for (int i = tid; i < 2 * PANEL + 32; i += 1024) SH[i] = (_Float16)0.0f;
  block_sync();
  if (tid < 16) {  // stage x[0] into parity-0 panel
    *(halfx8*)&SH[(tid >> 1) * SROW + XO + (tid & 1) * 8] =
        ld8(xg, ((long)0 * BB + rowbase + (tid >> 1)) * DD + (tid & 1) * 8);
  }

  // Cell ownership: (unit 4W+g, row c&7). Lanes c<8 own L0 (cA) and L1 (cB);
  // lanes c>=8 own L2 (cA). m8 also selects the odd K-tile for paired reads.
  const bool m8 = (c >= 8);
  const int r_el = c & 7;
  const int u_el = 4 * W + g;
  const int rd_offP = r_el * SROW + 8 * g + (m8 ? 32 : 0);
  const int rd_offX = r_el * SROW + 8 * g + XO;
  const int wrA = r_el * SROW + u_el + (m8 ? H2O : H0O);
  const int wrB = r_el * SROW + u_el + H1O;
  const long olane = ((long)rowbase + r_el) * HH + u_el;
  float cA = 0.f, cB = 0.f;

#pragma unroll 1
  for (int s2 = 0; s2 < (TT + 2) / 2; ++s2) {
    const int s = 2 * s2;
    BODY(s, 0, PANEL)
    BODY(s + 1, PANEL, 0)
  }
}

extern "C" void kernel_launch(void* const* d_in, const int* in_sizes, int n_in,
                              void* d_out, int out_size, void* d_ws, size_t ws_size,
                              hipStream_t stream) {
  (void)in_sizes; (void)n_in; (void)out_size;
  int* flag = (ws_size >= sizeof(int)) ? (int*)d_ws : nullptr;
  if (flag) {
    detect_k<<<dim3(1), dim3(64), 0, stream>>>((const unsigned short*)d_in[0], flag);
  }
  lstm3_k<<<dim3(BB / 8), dim3(1024), 0, stream>>>(
      d_in[0],
      d_in[1], d_in[2], d_in[3], d_in[4],
      d_in[5], d_in[6], d_in[7], d_in[8],
      d_in[9], d_in[10], d_in[11], d_in[12],
      d_out, flag);
}

// Round 11
// 274.320 us; speedup vs baseline: 1.1268x; 1.1268x over previous
//
#include <hip/hip_runtime.h>
#include <hip/hip_bf16.h>

// RecurrentLSTMStack: T=256, B=2048, D=16, H=64, 3 layers.
// R11: R10 with the cB state-consistency fix. R10's guard-free steady body
// let m8 lanes write h1 to the same LDS addr as their partner lane assuming
// bit-duplicate values — but m8 lanes' cB was never initialized (the !m8
// guard in the prologue skipped their state update), so their h1 diverged
// and corrupted the panel (absmax 7.8e-3). Fix: update cB on ALL lanes in
// the guarded bodies; m8's cB trajectory is then bit-identical (duplicate
// MFMA cols + same instruction sequence) and the unguarded write is benign.
// Rest of R10 kept: 16 waves, 2-seq nonlin, paired rcps (5->3 per cell),
// guard-free steady body, incremental out/x pointers, log2e folded weights.

#define TT 256
#define BB 2048
#define DD 16
#define HH 64

#define SROW 232                 // halves/row (24-half row pad; x over-reads hit zeros)
#define PANEL (8 * SROW)
#define H0O 0
#define H1O 64
#define H2O 128
#define XO  192

#define L2E  1.4426950408889634f
#define L2E2 2.8853900817779268f

typedef __attribute__((ext_vector_type(8))) _Float16 halfx8;
typedef __attribute__((ext_vector_type(8))) unsigned short ushortx8;
typedef __attribute__((ext_vector_type(4))) float floatx4;

#if __has_builtin(__builtin_amdgcn_exp2f)
#define EXP2F(x) __builtin_amdgcn_exp2f(x)
#else
#define EXP2F(x) exp2f(x)
#endif
#if __has_builtin(__builtin_amdgcn_rcpf)
#define RCPF(x) __builtin_amdgcn_rcpf(x)
#else
#define RCPF(x) (1.0f/(x))
#endif

// gv pre-scaled: i,f,o by L2E; g by L2E2. Paired rcps: 3 rcp instead of 5.
__device__ __forceinline__ float lstm_cell(const floatx4 gv, float& cSt) {
  float Ei = EXP2F(-gv[0]), Ef = EXP2F(-gv[1]);
  float Eg = EXP2F(gv[2]),  Eo = EXP2F(-gv[3]);
  float Ai = 1.0f + Ei, Bf = 1.0f + Ef, Cg = 1.0f + Eg, Do = 1.0f + Eo;
  float r1 = RCPF(Ai * Cg), r2 = RCPF(Bf * Do);
  float I = r1 * Cg, G = 1.0f - 2.0f * (r1 * Ai);
  float F = r2 * Do, O = r2 * Bf;
  float cn = F * cSt + I * G;
  cSt = cn;
  float Fc = 1.0f + EXP2F(L2E2 * cn);
  return O * (1.0f - 2.0f * RCPF(Fc));
}

// Raw barrier: waits our ds ops, does NOT drain vmcnt (x prefetch + out stores
// stay in flight).
__device__ __forceinline__ void block_sync() {
  asm volatile("s_waitcnt lgkmcnt(0)" ::: "memory");
  __builtin_amdgcn_s_barrier();
}

__global__ void detect_k(const unsigned short* __restrict__ xr, int* __restrict__ flag) {
  int cnt = 0;
  for (int i = threadIdx.x; i < 4096; i += 64) {
    float v = __uint_as_float(((unsigned int)xr[i]) << 16);
    if (!(fabsf(v) < 4.0f)) cnt++;
  }
#pragma unroll
  for (int o = 32; o > 0; o >>= 1) cnt += __shfl_down(cnt, o, 64);
  if (threadIdx.x == 0) flag[0] = (cnt < 100) ? 1 : 0;
}

#define MF(A, B, C) __builtin_amdgcn_mfma_f32_16x16x32_f16(A, B, C, 0, 0, 0)

// reads + 11 MFMAs; leaves a0,a1,a2 in scope (a1 last -> seq A starts early)
#define READS_MFMA(PPB)                                                           \
    const _Float16* PpR = SH + (PPB) + rd_off;                                    \
    halfx8 r0 = *(const halfx8*)(PpR + 0);                                        \
    halfx8 r1 = *(const halfx8*)(PpR + 32);                                       \
    halfx8 r2 = *(const halfx8*)(PpR + 64);                                       \
    halfx8 r3 = *(const halfx8*)(PpR + 96);                                      \
    halfx8 r4 = *(const halfx8*)(PpR + 128);                                      \
    halfx8 r5 = *(const halfx8*)(PpR + 160);                                      \
    halfx8 r6 = *(const halfx8*)(PpR + 192);                                      \
    floatx4 a0 = bs0, a1 = bs1, a2 = bs2;                                         \
    __builtin_amdgcn_s_setprio(1);                                                \
    a0 = MF(wA0[0], r0, a0); a2 = MF(wA2[0], r2, a2);                             \
    a0 = MF(wA0[1], r1, a0); a2 = MF(wA2[1], r3, a2);                             \
    a2 = MF(wA2[2], r4, a2); a0 = MF(wA0[2], r6, a0);                             \
    a2 = MF(wA2[3], r5, a2);                                                      \
    a1 = MF(wA1[0], r0, a1); a1 = MF(wA1[1], r1, a1);                             \
    a1 = MF(wA1[2], r2, a1); a1 = MF(wA1[3], r3, a1);                             \
    __builtin_amdgcn_s_setprio(0);

// fully-guarded body (prologue/epilogue only: s = 0,1,254,255,256,257).
// NOTE: cB state updates on ALL lanes (m8 included) so the steady body's
// unguarded same-address h1 writes are bit-identical duplicates.
#define BODY_G(S_, PPB, PNB)                                                      \
  {                                                                               \
    const int s_ = (S_);                                                          \
    halfx8 xreg = {};                                                             \
    const bool loader = (tid < 16) && (s_ + 1 < TT);                              \
    if (loader)                                                                   \
      xreg = ld8(xg, ((long)(s_ + 1) * BB + rowbase + (tid >> 1)) * DD + (tid & 1) * 8); \
    block_sync();                                                                 \
    READS_MFMA(PPB)                                                               \
    _Float16* Pn = SH + (PNB);                                                    \
    { floatx4 gv;                                                                 \
      gv[0] = m8 ? a2[0] : a0[0]; gv[1] = m8 ? a2[1] : a0[1];                     \
      gv[2] = m8 ? a2[2] : a0[2]; gv[3] = m8 ? a2[3] : a0[3];                     \
      float ct = cA;                                                              \
      float hn = lstm_cell(gv, ct);                                               \
      bool vA = m8 ? (s_ >= 2) : (s_ < TT);                                       \
      if (vA) {                                                                   \
        cA = ct; Pn[wrA] = (_Float16)hn;                                          \
        if (m8) {                                                                 \
          long oi = (long)(s_ - 2) * ((long)BB * HH) + olane;                     \
          if (isbf) ((__hip_bfloat16*)outp)[oi] = __float2bfloat16(hn);           \
          else ((float*)outp)[oi] = hn;                                           \
        }                                                                         \
      }                                                                           \
    }                                                                             \
    { float ct = cB;                                                              \
      float hn = lstm_cell(a1, ct);                                               \
      if (s_ >= 1 && s_ <= TT) { cB = ct; Pn[wrB] = (_Float16)hn; }               \
    }                                                                             \
    if (loader) *(halfx8*)&Pn[xwr] = xreg;                                        \
  }

// guard-free steady body (s in [2,253]: all layers active, loader always on)
#define BODY_F(PPB, PNB)                                                          \
  {                                                                               \
    halfx8 xreg = {};                                                             \
    const bool loader = (tid < 16);                                               \
    if (loader) xreg = ld8(xg, xbase + xlane);                                    \
    block_sync();                                                                 \
    READS_MFMA(PPB)                                                               \
    _Float16* Pn = SH + (PNB);                                                    \
    { floatx4 gv;                                                                 \
      gv[0] = m8 ? a2[0] : a0[0]; gv[1] = m8 ? a2[1] : a0[1];                     \
      gv[2] = m8 ? a2[2] : a0[2]; gv[3] = m8 ? a2[3] : a0[3];                     \
      float hn = lstm_cell(gv, cA);                                               \
      Pn[wrA] = (_Float16)hn;                                                     \
      if (m8) {                                                                   \
        if (isbf) *(__hip_bfloat16*)op = __float2bfloat16(hn);                    \
        else      *(float*)op = hn;                                               \
      }                                                                           \
    }                                                                             \
    op += ostep;                                                                  \
    { float hn = lstm_cell(a1, cB);                                               \
      Pn[wrB] = (_Float16)hn;   /* all lanes: bit-identical dup on m8 */          \
    }                                                                             \
    if (loader) *(halfx8*)&Pn[xwr] = xreg;                                        \
    xbase += (long)BB * DD;                                                       \
  }

__launch_bounds__(1024, 1)
__global__ void lstm3_k(const void* __restrict__ xg,
                        const void* W0i, const void* W0h, const void* B0i, const void* B0h,
                        const void* W1i, const void* W1h, const void* B1i, const void* B1h,
                        const void* W2i, const void* W2h, const void* B2i, const void* B2h,
                        void* __restrict__ outp, const int* __restrict__ flagp) {
  const int tid = threadIdx.x;
  const int W = tid >> 6;        // wave 0..15 = M-tile index
  const int lane = tid & 63;
  const int c = lane & 15;       // MFMA col (batch row c&7, dup pair c/c+8)
  const int g = lane >> 4;       // k-slot group
  const int rowbase = blockIdx.x * 8;
  const int isbf = flagp ? flagp[0] : 1;

  // Panel row r: [h0(0..63) | h1(64..127) | h2(128..191) | x(192..207) | pad(..231)]
  __shared__ __align__(16) _Float16 SH[2 * PANEL + 32];

  auto ldf = [&](const void* b, long i) -> float {
    return isbf ? __bfloat162float(((const __hip_bfloat16*)b)[i]) : ((const float*)b)[i];
  };
  auto ld8 = [&](const void* b, long i) -> halfx8 {
    halfx8 r;
    if (isbf) {
      ushortx8 raw = *(const ushortx8*)((const unsigned short*)b + i);
#pragma unroll
      for (int j = 0; j < 8; ++j)
        r[j] = (_Float16)__uint_as_float(((unsigned int)raw[j]) << 16);
    } else {
      const float* s = (const float*)b + i;
#pragma unroll
      for (int j = 0; j < 8; ++j) r[j] = (_Float16)s[j];
    }
    return r;
  };
  auto ld8s = [&](const void* b, long i, float sc) -> halfx8 {  // scaled weight load
    halfx8 r;
    if (isbf) {
      ushortx8 raw = *(const ushortx8*)((const unsigned short*)b + i);
#pragma unroll
      for (int j = 0; j < 8; ++j)
        r[j] = (_Float16)(sc * __uint_as_float(((unsigned int)raw[j]) << 16));
    } else {
      const float* s = (const float*)b + i;
#pragma unroll
      for (int j = 0; j < 8; ++j) r[j] = (_Float16)(sc * s[j]);
    }
    return r;
  };

  // ---- persistent weight fragments (ONE M-tile per wave) + combined biases ----
  // Interleaved gate rows: r_il = 4*unit + q <-> orig row q*64 + unit.
  // Gate q scale: i,f,o -> L2E; g -> L2E2 (log2e folded; exp2 used directly).
  halfx8 wA0[3], wA1[4], wA2[4];
  floatx4 bs0, bs1, bs2;
  {
    const int ril = W * 16 + c;
    const int u = ril >> 2, q = ril & 3;
    const long orig = q * 64 + u;
    const float sc = (q == 2) ? L2E2 : L2E;
    halfx8 z = {};
    wA0[0] = ld8s(W0h, orig * 64 + 8 * g, sc);
    wA0[1] = ld8s(W0h, orig * 64 + 32 + 8 * g, sc);
    wA0[2] = (g == 0) ? ld8s(W0i, orig * 16, sc)
           : (g == 1) ? ld8s(W0i, orig * 16 + 8, sc) : z;
    wA1[0] = ld8s(W1i, orig * 64 + 8 * g, sc);
    wA1[1] = ld8s(W1i, orig * 64 + 32 + 8 * g, sc);
    wA1[2] = ld8s(W1h, orig * 64 + 8 * g, sc);
    wA1[3] = ld8s(W1h, orig * 64 + 32 + 8 * g, sc);
    wA2[0] = ld8s(W2i, orig * 64 + 8 * g, sc);
    wA2[1] = ld8s(W2i, orig * 64 + 32 + 8 * g, sc);
    wA2[2] = ld8s(W2h, orig * 64 + 8 * g, sc);
    wA2[3] = ld8s(W2h, orig * 64 + 32 + 8 * g, sc);
    const int ub = 4 * W + g;
#pragma unroll
    for (int qq = 0; qq < 4; ++qq) {
      const float bsc = (qq == 2) ? L2E2 : L2E;
      bs0[qq] = bsc * (ldf(B0i, 64 * qq + ub) + ldf(B0h, 64 * qq + ub));
      bs1[qq] = bsc * (ldf(B1i, 64 * qq + ub) + ldf(B1h, 64 * qq + ub));
      bs2[qq] = bsc * (ldf(B2i, 64 * qq + ub) + ldf(B2h, 64 * qq + ub));
    }
  }

  for (int i = tid; i < 2 * PANEL + 32; i += 1024) SH[i] = (_Float16)0.0f;
  block_sync();
  if (tid < 16) {  // stage x[0] into parity-0 panel
    *(halfx8*)&SH[(tid >> 1) * SROW + XO + (tid & 1) * 8] =
        ld8(xg, ((long)0 * BB + rowbase + (tid >> 1)) * DD + (tid & 1) * 8);
  }

  // Cell ownership: (unit 4W+g, row c&7). Lanes c<8 own L0 (cA) and L1 (cB);
  // lanes c>=8 own L2 (cA). m8 lanes also track cB (bit-identical dup).
  const bool m8 = (c >= 8);
  const int r_el = c & 7;
  const int u_el = 4 * W + g;
  const int rd_off = r_el * SROW + 8 * g;
  const int wrA = r_el * SROW + u_el + (m8 ? H2O : H0O);
  const int wrB = r_el * SROW + u_el + H1O;
  const int xwr = (tid >> 1) * SROW + XO + (tid & 1) * 8;
  const int xlane = (rowbase + (tid >> 1)) * DD + (tid & 1) * 8;
  const long olane = ((long)rowbase + r_el) * HH + u_el;
  const long ostep = (long)BB * HH * (isbf ? 2 : 4);
  char* op = (char*)outp + (isbf ? 2 : 4) * olane;   // -> element (t=0, row, unit)
  float cA = 0.f, cB = 0.f;
  long xbase = (long)3 * BB * DD;                    // first FAST prefetches x[3]

  BODY_G(0, 0, PANEL)
  BODY_G(1, PANEL, 0)
#pragma unroll 1
  for (int s2 = 1; s2 < 127; ++s2) {   // s = 2..253
    BODY_F(0, PANEL)
    BODY_F(PANEL, 0)
  }
  BODY_G(254, 0, PANEL)
  BODY_G(255, PANEL, 0)
  BODY_G(256, 0, PANEL)
  BODY_G(257, PANEL, 0)
}

extern "C" void kernel_launch(void* const* d_in, const int* in_sizes, int n_in,
                              void* d_out, int out_size, void* d_ws, size_t ws_size,
                              hipStream_t stream) {
  (void)in_sizes; (void)n_in; (void)out_size;
  int* flag = (ws_size >= sizeof(int)) ? (int*)d_ws : nullptr;
  if (flag) {
    detect_k<<<dim3(1), dim3(64), 0, stream>>>((const unsigned short*)d_in[0], flag);
  }
  lstm3_k<<<dim3(BB / 8), dim3(1024), 0, stream>>>(
      d_in[0],
      d_in[1], d_in[2], d_in[3], d_in[4],
      d_in[5], d_in[6], d_in[7], d_in[8],
      d_in[9], d_in[10], d_in[11], d_in[12],
      d_out, flag);
}